// Round 6
// baseline (111.099 us; speedup 1.0000x reference)
//
#include <hip/hip_runtime.h>
#include <hip/hip_bf16.h>

// DistMult edge score: out[e] = sum_d node_emb[src[e]][d] * rel_emb[e][d] * node_emb[dst[e]][d]
// N_NODES=100000, N_EDGES=1000000, DIM=64 (fp32).
//
// Model (R4/R5): the limiter is bytes crossing the per-XCD L2-miss boundary
// (~6.2 TB/s aggregate). R5 (bf16 table) = 86 us ~= 528 MB. Back-solve says
// gathers still miss ~87%: a 12.8 MB table can't stay resident in a 4 MB
// per-XCD L2 under the rel stream.
//
// R6 lever: DIM-SPLIT. Score in two passes over the D axis (d<32, d>=32),
// accumulating into out. Per-pass table slice = 6.4 MB (~L2-sized), each
// gather = exactly one 64 B line. nt hints on the streams (rel/src/dst/out)
// discourage L2 allocation so the table slice survives. Cross-kernel
// accumulation is safe: kernel-boundary release/acquire flushes L2 (same
// mechanism the bf16 table hand-off already relies on).
// Cost model: rel 256 + idx 16 + out 12 + gather-miss ~100-190 + convert 38
//   => 66-81 us (center ~72) vs 85.8 now.

#define DIM 64
#define HALF_DIM 32
#define LANES_PER_EDGE 8   // 8 lanes x float4 = 32 floats = half a row

typedef __attribute__((ext_vector_type(4))) float  float4n;
typedef __attribute__((ext_vector_type(4))) unsigned short ushort4n;

__device__ __forceinline__ float bf2f(unsigned short u) {
    unsigned int x = ((unsigned int)u) << 16;
    return __builtin_bit_cast(float, x);
}

__device__ __forceinline__ unsigned short f2bf_rne(float f) {
    unsigned int x = __builtin_bit_cast(unsigned int, f);
    unsigned int lsb = (x >> 16) & 1u;
    x += 0x7fffu + lsb;
    return (unsigned short)(x >> 16);
}

__global__ __launch_bounds__(256) void convert_nodes_kernel(
    const float* __restrict__ node_emb,
    unsigned short* __restrict__ node_bf,
    int n_elems4)  // number of float4 groups
{
    int i = blockIdx.x * blockDim.x + threadIdx.x;
    const int stride = gridDim.x * blockDim.x;
    for (; i < n_elems4; i += stride) {
        const float4n v = *reinterpret_cast<const float4n*>(node_emb + (size_t)i * 4);
        ushort4n o;
        o.x = f2bf_rne(v.x);
        o.y = f2bf_rne(v.y);
        o.z = f2bf_rne(v.z);
        o.w = f2bf_rne(v.w);
        *reinterpret_cast<ushort4n*>(node_bf + (size_t)i * 4) = o;
    }
}

// One D-half per launch. PASS=0: out = p (d<32). PASS=1: out += p (d>=32).
template <int PASS>
__global__ __launch_bounds__(256) void distmult_score_half_kernel(
    const unsigned short* __restrict__ node_bf,
    const float* __restrict__ rel_emb,
    const int* __restrict__ src,
    const int* __restrict__ dst,
    float* __restrict__ out,
    int n_edges)
{
    const int tid   = blockIdx.x * blockDim.x + threadIdx.x;
    const int lane  = tid & (LANES_PER_EDGE - 1);
    const int group = tid >> 3;
    const int n_groups = (gridDim.x * blockDim.x) >> 3;
    const int off = PASS * HALF_DIM + lane * 4;  // element offset within row

    for (int e = group; e < n_edges; e += n_groups) {
        const int s = __builtin_nontemporal_load(src + e);
        const int d = __builtin_nontemporal_load(dst + e);

        // rel: pure stream, nt. node gathers: plain loads (we WANT residency).
        const float4n  r = __builtin_nontemporal_load(
            reinterpret_cast<const float4n*>(rel_emb + (size_t)e * DIM + off));
        const ushort4n h = *reinterpret_cast<const ushort4n*>(node_bf + (size_t)s * DIM + off);
        const ushort4n t = *reinterpret_cast<const ushort4n*>(node_bf + (size_t)d * DIM + off);

        float p = bf2f(h.x) * r.x * bf2f(t.x)
                + bf2f(h.y) * r.y * bf2f(t.y)
                + bf2f(h.z) * r.z * bf2f(t.z)
                + bf2f(h.w) * r.w * bf2f(t.w);

        // Reduce across the 8 lanes of this edge's group.
        p += __shfl_xor(p, 1, 64);
        p += __shfl_xor(p, 2, 64);
        p += __shfl_xor(p, 4, 64);

        if (lane == 0) {
            if (PASS == 0) {
                __builtin_nontemporal_store(p, out + e);
            } else {
                const float prev = out[e];
                __builtin_nontemporal_store(prev + p, out + e);
            }
        }
    }
}

// fp32 fallback (R1 structure) in case ws_size < bf16 table size.
__global__ __launch_bounds__(256) void distmult_score_f32_kernel(
    const float* __restrict__ node_emb,
    const float* __restrict__ rel_emb,
    const int* __restrict__ src,
    const int* __restrict__ dst,
    float* __restrict__ out,
    int n_edges)
{
    const int tid   = blockIdx.x * blockDim.x + threadIdx.x;
    const int lane  = tid & 15;
    const int group = tid >> 4;
    const int n_groups = (gridDim.x * blockDim.x) >> 4;
    const int off = lane * 4;

    for (int e = group; e < n_edges; e += n_groups) {
        const int s = src[e];
        const int d = dst[e];
        const float4n r = *reinterpret_cast<const float4n*>(rel_emb  + (size_t)e * DIM + off);
        const float4n h = *reinterpret_cast<const float4n*>(node_emb + (size_t)s * DIM + off);
        const float4n t = *reinterpret_cast<const float4n*>(node_emb + (size_t)d * DIM + off);

        float p = h.x * r.x * t.x + h.y * r.y * t.y + h.z * r.z * t.z + h.w * r.w * t.w;
        p += __shfl_xor(p, 1, 64);
        p += __shfl_xor(p, 2, 64);
        p += __shfl_xor(p, 4, 64);
        p += __shfl_xor(p, 8, 64);
        if (lane == 0) out[e] = p;
    }
}

extern "C" void kernel_launch(void* const* d_in, const int* in_sizes, int n_in,
                              void* d_out, int out_size, void* d_ws, size_t ws_size,
                              hipStream_t stream) {
    const float* node_emb = (const float*)d_in[0];
    const float* rel_emb  = (const float*)d_in[1];
    const int*   src      = (const int*)d_in[2];
    const int*   dst      = (const int*)d_in[3];
    float*       out      = (float*)d_out;

    const int n_edges      = in_sizes[2];   // src has one entry per edge
    const int n_node_elems = in_sizes[0];   // N_NODES * DIM
    const size_t bf_bytes  = (size_t)n_node_elems * sizeof(unsigned short);

    const int block = 256;

    if (ws_size >= bf_bytes) {
        unsigned short* node_bf = (unsigned short*)d_ws;
        const int n4 = n_node_elems / 4;
        int cgrid = (n4 + block - 1) / block;
        if (cgrid > 2048) cgrid = 2048;
        convert_nodes_kernel<<<cgrid, block, 0, stream>>>(node_emb, node_bf, n4);

        long long blocks_needed = ((long long)n_edges * LANES_PER_EDGE + block - 1) / block;
        int grid = (int)(blocks_needed < 2048 ? blocks_needed : 2048);
        distmult_score_half_kernel<0><<<grid, block, 0, stream>>>(node_bf, rel_emb, src, dst, out, n_edges);
        distmult_score_half_kernel<1><<<grid, block, 0, stream>>>(node_bf, rel_emb, src, dst, out, n_edges);
    } else {
        long long blocks_needed = ((long long)n_edges * 16 + block - 1) / block;
        int grid = (int)(blocks_needed < 2048 ? blocks_needed : 2048);
        distmult_score_f32_kernel<<<grid, block, 0, stream>>>(node_emb, rel_emb, src, dst, out, n_edges);
    }
}

// Round 7
// 86.550 us; speedup vs baseline: 1.2836x; 1.2836x over previous
//
#include <hip/hip_runtime.h>
#include <hip/hip_bf16.h>

// DistMult edge score: out[e] = sum_d node_emb[src[e]][d] * rel_emb[e][d] * node_emb[dst[e]][d]
// N_NODES=100000, N_EDGES=1000000, DIM=64 (fp32).
//
// Model (R4/R5/R6): limiter is the L2-miss/fabric path (~6.6 TB/s).
// R5 (bf16 table, one pass) = 85.8 us ~= 524 MB: rel 256 + idx 8 + out 4 +
// gather-misses ~210 (random 128 B lines over 12.8 MB table, 4 MB/XCD L2,
// hit ~18%). R6 dim-split REGRESSED (6.4 MB slice still > 4 MB L2 per XCD,
// plus extra idx/out/launch costs) -> reverted.
//
// R7 single lever: nt hints on the STREAMS ONLY (rel, src, dst loads; out
// store), table gathers stay cacheable. Goal: stop the rel stream (32 MB/XCD
// per dispatch) from churning L2 so gather hit rises toward its ~30%
// steady-state. Predict score ~75 us, total 80-83. Null => R5 is the floor.

#define DIM 64
#define LANES_PER_EDGE 16

typedef __attribute__((ext_vector_type(4))) float  float4n;
typedef __attribute__((ext_vector_type(4))) unsigned short ushort4n;

__device__ __forceinline__ float bf2f(unsigned short u) {
    unsigned int x = ((unsigned int)u) << 16;
    return __builtin_bit_cast(float, x);
}

__device__ __forceinline__ unsigned short f2bf_rne(float f) {
    unsigned int x = __builtin_bit_cast(unsigned int, f);
    unsigned int lsb = (x >> 16) & 1u;
    x += 0x7fffu + lsb;
    return (unsigned short)(x >> 16);
}

__global__ __launch_bounds__(256) void convert_nodes_kernel(
    const float* __restrict__ node_emb,
    unsigned short* __restrict__ node_bf,
    int n_elems4)  // number of float4 groups
{
    int i = blockIdx.x * blockDim.x + threadIdx.x;
    const int stride = gridDim.x * blockDim.x;
    for (; i < n_elems4; i += stride) {
        const float4n v = *reinterpret_cast<const float4n*>(node_emb + (size_t)i * 4);
        ushort4n o;
        o.x = f2bf_rne(v.x);
        o.y = f2bf_rne(v.y);
        o.z = f2bf_rne(v.z);
        o.w = f2bf_rne(v.w);
        *reinterpret_cast<ushort4n*>(node_bf + (size_t)i * 4) = o;
    }
}

__global__ __launch_bounds__(256) void distmult_score_bf16_kernel(
    const unsigned short* __restrict__ node_bf,
    const float* __restrict__ rel_emb,
    const int* __restrict__ src,
    const int* __restrict__ dst,
    float* __restrict__ out,
    int n_edges)
{
    const int tid   = blockIdx.x * blockDim.x + threadIdx.x;
    const int lane  = tid & (LANES_PER_EDGE - 1);
    const int group = tid >> 4;
    const int n_groups = (gridDim.x * blockDim.x) >> 4;
    const int off = lane * 4;

    for (int e = group; e < n_edges; e += 2 * n_groups) {
        const int e2 = e + n_groups;
        const bool has2 = (e2 < n_edges);

        // Streams: nt (evict-first) so they don't churn L2.
        const int s1 = __builtin_nontemporal_load(src + e);
        const int d1 = __builtin_nontemporal_load(dst + e);
        const int s2 = has2 ? __builtin_nontemporal_load(src + e2) : 0;
        const int d2 = has2 ? __builtin_nontemporal_load(dst + e2) : 0;

        const float4n r1 = __builtin_nontemporal_load(
            reinterpret_cast<const float4n*>(rel_emb + (size_t)e * DIM + off));
        // Table gathers: plain cacheable loads (we WANT L2 residency).
        const ushort4n h1 = *reinterpret_cast<const ushort4n*>(node_bf + (size_t)s1 * DIM + off);
        const ushort4n t1 = *reinterpret_cast<const ushort4n*>(node_bf + (size_t)d1 * DIM + off);

        float4n  r2 = {0,0,0,0};
        ushort4n h2 = {0,0,0,0}, t2 = {0,0,0,0};
        if (has2) {
            r2 = __builtin_nontemporal_load(
                reinterpret_cast<const float4n*>(rel_emb + (size_t)e2 * DIM + off));
            h2 = *reinterpret_cast<const ushort4n*>(node_bf + (size_t)s2 * DIM + off);
            t2 = *reinterpret_cast<const ushort4n*>(node_bf + (size_t)d2 * DIM + off);
        }

        float p1 = bf2f(h1.x) * r1.x * bf2f(t1.x)
                 + bf2f(h1.y) * r1.y * bf2f(t1.y)
                 + bf2f(h1.z) * r1.z * bf2f(t1.z)
                 + bf2f(h1.w) * r1.w * bf2f(t1.w);

        p1 += __shfl_xor(p1, 1, 64);
        p1 += __shfl_xor(p1, 2, 64);
        p1 += __shfl_xor(p1, 4, 64);
        p1 += __shfl_xor(p1, 8, 64);
        if (lane == 0) __builtin_nontemporal_store(p1, out + e);

        if (has2) {
            float p2 = bf2f(h2.x) * r2.x * bf2f(t2.x)
                     + bf2f(h2.y) * r2.y * bf2f(t2.y)
                     + bf2f(h2.z) * r2.z * bf2f(t2.z)
                     + bf2f(h2.w) * r2.w * bf2f(t2.w);

            p2 += __shfl_xor(p2, 1, 64);
            p2 += __shfl_xor(p2, 2, 64);
            p2 += __shfl_xor(p2, 4, 64);
            p2 += __shfl_xor(p2, 8, 64);
            if (lane == 0) __builtin_nontemporal_store(p2, out + e2);
        }
    }
}

// fp32 fallback (R1 structure) in case ws_size < bf16 table size.
__global__ __launch_bounds__(256) void distmult_score_f32_kernel(
    const float* __restrict__ node_emb,
    const float* __restrict__ rel_emb,
    const int* __restrict__ src,
    const int* __restrict__ dst,
    float* __restrict__ out,
    int n_edges)
{
    const int tid   = blockIdx.x * blockDim.x + threadIdx.x;
    const int lane  = tid & 15;
    const int group = tid >> 4;
    const int n_groups = (gridDim.x * blockDim.x) >> 4;
    const int off = lane * 4;

    for (int e = group; e < n_edges; e += n_groups) {
        const int s = src[e];
        const int d = dst[e];
        const float4n r = *reinterpret_cast<const float4n*>(rel_emb  + (size_t)e * DIM + off);
        const float4n h = *reinterpret_cast<const float4n*>(node_emb + (size_t)s * DIM + off);
        const float4n t = *reinterpret_cast<const float4n*>(node_emb + (size_t)d * DIM + off);

        float p = h.x * r.x * t.x + h.y * r.y * t.y + h.z * r.z * t.z + h.w * r.w * t.w;
        p += __shfl_xor(p, 1, 64);
        p += __shfl_xor(p, 2, 64);
        p += __shfl_xor(p, 4, 64);
        p += __shfl_xor(p, 8, 64);
        if (lane == 0) out[e] = p;
    }
}

extern "C" void kernel_launch(void* const* d_in, const int* in_sizes, int n_in,
                              void* d_out, int out_size, void* d_ws, size_t ws_size,
                              hipStream_t stream) {
    const float* node_emb = (const float*)d_in[0];
    const float* rel_emb  = (const float*)d_in[1];
    const int*   src      = (const int*)d_in[2];
    const int*   dst      = (const int*)d_in[3];
    float*       out      = (float*)d_out;

    const int n_edges      = in_sizes[2];   // src has one entry per edge
    const int n_node_elems = in_sizes[0];   // N_NODES * DIM
    const size_t bf_bytes  = (size_t)n_node_elems * sizeof(unsigned short);

    const int block = 256;
    long long blocks_needed = ((long long)n_edges * LANES_PER_EDGE + block - 1) / block;
    int grid = (int)(blocks_needed < 2048 ? blocks_needed : 2048);

    if (ws_size >= bf_bytes) {
        unsigned short* node_bf = (unsigned short*)d_ws;
        const int n4 = n_node_elems / 4;
        int cgrid = (n4 + block - 1) / block;
        if (cgrid > 2048) cgrid = 2048;
        convert_nodes_kernel<<<cgrid, block, 0, stream>>>(node_emb, node_bf, n4);
        distmult_score_bf16_kernel<<<grid, block, 0, stream>>>(node_bf, rel_emb, src, dst, out, n_edges);
    } else {
        distmult_score_f32_kernel<<<grid, block, 0, stream>>>(node_emb, rel_emb, src, dst, out, n_edges);
    }
}